// Round 1
// baseline (335.443 us; speedup 1.0000x reference)
//
#include <hip/hip_runtime.h>

#define DEVI __device__ __forceinline__

DEVI float shx(float v, int m) { return __shfl_xor(v, m, 64); }

// In-thread FWHT over N contiguous elements.
template<int N>
DEVI void fwht_local(float* v) {
#pragma unroll
  for (int s = 1; s < N; s <<= 1) {
#pragma unroll
    for (int k = 0; k < N; ++k) {
      if ((k & s) == 0) {
        float a = v[k], b = v[k | s];
        v[k] = a + b;
        v[k | s] = a - b;
      }
    }
  }
}

// Cross-lane butterfly: partner = lane ^ mask. up: keep a+b, else b-a.
template<int N>
DEVI void xbfly(float* v, int mask, int up) {
  const float sgn = up ? 1.0f : -1.0f;
#pragma unroll
  for (int k = 0; k < N; ++k) {
    float u = shx(v[k], mask);
    v[k] = fmaf(sgn, v[k], u);  // up: v+u ; down: u-v
  }
}

// 32x32 2D FWHT (unnormalized). Lane t holds row r=t>>1, cols (t&1)*16+k.
DEVI void fwht2d32(float v[16], int t) {
  fwht_local<16>(v);              // row strides 1,2,4,8 (intra-thread)
  xbfly<16>(v, 1, !(t & 1));      // row stride 16
  const int r = t >> 1;
  xbfly<16>(v, 2, !(r & 1));      // col strides 1..16
  xbfly<16>(v, 4, !(r & 2));
  xbfly<16>(v, 8, !(r & 4));
  xbfly<16>(v, 16, !(r & 8));
  xbfly<16>(v, 32, !(r & 16));
}

// 16x16 2D FWHT (unnormalized). Lane l holds row r=l>>2, cols (l&3)*4+j.
DEVI void fwht2d16(float v[4], int l) {
  fwht_local<4>(v);               // row strides 1,2
  xbfly<4>(v, 1, !(l & 1));       // row stride 4
  xbfly<4>(v, 2, !(l & 2));       // row stride 8
  const int r = l >> 2;
  xbfly<4>(v, 4, !(r & 1));       // col strides 1..8
  xbfly<4>(v, 8, !(r & 2));
  xbfly<4>(v, 16, !(r & 4));
  xbfly<4>(v, 32, !(r & 8));
}

// ---------------------------------------------------------------- filters
__global__ __launch_bounds__(64) void k_filters(
    const float* __restrict__ f1, const float* __restrict__ f2,
    float* __restrict__ kt1, float* __restrict__ kt2) {
  const int blk = blockIdx.x;
  const int t = threadIdx.x;
  if (blk < 32) {
    const int f = blk;
    const int r = t >> 1, h = t & 1;
    float v[16];
#pragma unroll
    for (int k = 0; k < 16; ++k) {
      const int c = h * 16 + k;
      v[k] = (r < 3 && c < 3) ? f1[f * 9 + r * 3 + c] : 0.0f;
    }
    fwht2d32(v, t);
    float* dst = kt1 + f * 1024 + t * 16;  // row-major: idx = r*32+c = t*16+k
#pragma unroll
    for (int k = 0; k < 16; ++k) dst[k] = v[k];
  } else {
    const int g = blk - 32;
    const int r = t >> 2, q = t & 3;
    float v[4];
#pragma unroll
    for (int j = 0; j < 4; ++j) {
      const int c = q * 4 + j;
      v[j] = (r < 3 && c < 3) ? f2[g * 9 + r * 3 + c] : 0.0f;
    }
    fwht2d16(v, t);
    float* dst = kt2 + g * 256 + t * 4;    // row-major: idx = r*16+c = 4l+j
#pragma unroll
    for (int j = 0; j < 4; ++j) dst[j] = v[j];
  }
}

// ---------------------------------------------------------- fused conv1+conv2
// One block per batch item. 4 waves; each wave owns 8 conv1 filters and
// 16 conv2 filters. out1 is never materialized: pooled relu'd conv1 maps are
// accumulated into the channel-sum S2 directly.
__global__ __launch_bounds__(256) void k_conv(
    const float* __restrict__ x,
    const float* __restrict__ bias1,
    const float* __restrict__ bias2,
    const float* __restrict__ kt1,
    const float* __restrict__ kt2,
    float* __restrict__ out2) {
  __shared__ float sS[1024];   // channel-sum S (32x32), later reused for S2
  __shared__ float sP[1024];   // 4 waves x 256 partial S2
  const int b = blockIdx.x;
  const int tid = threadIdx.x;

  // Phase 1: S = x[b,0]+x[b,1]+x[b,2]
  const float* xb = x + (size_t)b * 3072;
  {
    const int i = tid * 4;
    float4 a0 = *(const float4*)(xb + i);
    float4 a1 = *(const float4*)(xb + 1024 + i);
    float4 a2 = *(const float4*)(xb + 2048 + i);
    float4 s;
    s.x = a0.x + a1.x + a2.x;
    s.y = a0.y + a1.y + a2.y;
    s.z = a0.z + a1.z + a2.z;
    s.w = a0.w + a1.w + a2.w;
    *(float4*)(sS + i) = s;
  }
  __syncthreads();

  const int wv = tid >> 6;
  const int t = tid & 63;
  const int h = t & 1;

  // Phase 2: Ts = FWHT2D_32(S), per-wave in registers
  float Ts[16];
#pragma unroll
  for (int k4 = 0; k4 < 4; ++k4) {
    float4 v = *(const float4*)(sS + t * 16 + k4 * 4);
    Ts[k4 * 4 + 0] = v.x; Ts[k4 * 4 + 1] = v.y;
    Ts[k4 * 4 + 2] = v.z; Ts[k4 * 4 + 3] = v.w;
  }
  fwht2d32(Ts, t);

  // Phase 3: 8 conv1 filters per wave; accumulate pooled relu into acc
  float acc[8];
#pragma unroll
  for (int j = 0; j < 8; ++j) acc[j] = 0.0f;

  for (int i = 0; i < 8; ++i) {
    const int f = wv * 8 + i;
    const float* kp = kt1 + f * 1024 + t * 16;
    float u[16];
#pragma unroll
    for (int k4 = 0; k4 < 4; ++k4) {
      float4 v = *(const float4*)(kp + k4 * 4);
      u[k4 * 4 + 0] = Ts[k4 * 4 + 0] * v.x;
      u[k4 * 4 + 1] = Ts[k4 * 4 + 1] * v.y;
      u[k4 * 4 + 2] = Ts[k4 * 4 + 2] * v.z;
      u[k4 * 4 + 3] = Ts[k4 * 4 + 3] * v.w;
    }
    fwht2d32(u, t);
    const float bb = bias1[f];
#pragma unroll
    for (int k = 0; k < 16; ++k)
      u[k] = fmaxf(fmaf(u[k], 1.0f / 32768.0f, bb), 0.0f);
    // pool rows (2i,2i+1) -> partner lane t^2
#pragma unroll
    for (int k = 0; k < 16; ++k)
      u[k] = fmaxf(u[k], shx(u[k], 2));
    // pool cols within thread
#pragma unroll
    for (int j = 0; j < 8; ++j)
      acc[j] += fmaxf(u[2 * j], u[2 * j + 1]);
  }

  // Phase 4: combine partial S2 across waves
  if (!(t & 2)) {
    const int i16 = t >> 2;
    float* dst = sP + wv * 256 + i16 * 16 + h * 8;
#pragma unroll
    for (int j = 0; j < 8; ++j) dst[j] = acc[j];
  }
  __syncthreads();
  sS[tid] = sP[tid] + sP[tid + 256] + sP[tid + 512] + sP[tid + 768];
  __syncthreads();

  // Phase 5: Ts2 = FWHT2D_16(S2), per-wave
  const int l = t;
  const int q = l & 3;
  const int r2 = l >> 2;
  float T2[4];
#pragma unroll
  for (int j = 0; j < 4; ++j) T2[j] = sS[r2 * 16 + q * 4 + j];
  fwht2d16(T2, l);

  // Phase 6: 16 conv2 filters per wave -> out2 (B, 64, 8, 8) flat
  for (int i = 0; i < 16; ++i) {
    const int g = wv * 16 + i;
    float4 kv = *(const float4*)(kt2 + g * 256 + l * 4);
    float u2[4] = {T2[0] * kv.x, T2[1] * kv.y, T2[2] * kv.z, T2[3] * kv.w};
    fwht2d16(u2, l);
    const float bb = bias2[g];
#pragma unroll
    for (int j = 0; j < 4; ++j)
      u2[j] = fmaxf(fmaf(u2[j], 1.0f / 4096.0f, bb), 0.0f);
    // pool rows -> partner lane l^4
#pragma unroll
    for (int j = 0; j < 4; ++j)
      u2[j] = fmaxf(u2[j], shx(u2[j], 4));
    float2 p;
    p.x = fmaxf(u2[0], u2[1]);
    p.y = fmaxf(u2[2], u2[3]);
    if (!(l & 4)) {
      const int i8 = l >> 3;
      *(float2*)(out2 + (size_t)b * 4096 + g * 64 + i8 * 8 + q * 2) = p;
    }
  }
}

// ------------------------------------------------------------------- FC1
// C[m,n] = sum_k A[m,k]*W[n,k]; M=B, N=512, K=4096. Split-K=4, 64x64 tiles,
// 256 threads, 4x4 microtile, transposed LDS staging (stride 68 keeps 16B
// alignment for ds_read_b128).
__global__ __launch_bounds__(256) void k_fc1(
    const float* __restrict__ A, const float* __restrict__ W,
    float* __restrict__ P, int mtiles) {
  __shared__ float As[32][68];
  __shared__ float Ws[32][68];
  const int tiles = mtiles * 8;
  const int bz = blockIdx.x / tiles;
  const int rem = blockIdx.x % tiles;
  const int m0 = (rem >> 3) * 64;
  const int n0 = (rem & 7) * 64;
  const int k0 = bz * 1024;
  const int tid = threadIdx.x;
  const int tx = tid & 15, ty = tid >> 4;
  const int lrow = tid >> 3, lq = tid & 7;

  float acc[4][4];
#pragma unroll
  for (int i = 0; i < 4; ++i)
#pragma unroll
    for (int j = 0; j < 4; ++j) acc[i][j] = 0.0f;

  for (int kk = 0; kk < 1024; kk += 32) {
#pragma unroll
    for (int half = 0; half < 2; ++half) {
      const int row = lrow + half * 32;
      const float4 a4 =
          *(const float4*)&A[(size_t)(m0 + row) * 4096 + k0 + kk + lq * 4];
      As[lq * 4 + 0][row] = a4.x; As[lq * 4 + 1][row] = a4.y;
      As[lq * 4 + 2][row] = a4.z; As[lq * 4 + 3][row] = a4.w;
      const float4 w4 =
          *(const float4*)&W[(size_t)(n0 + row) * 4096 + k0 + kk + lq * 4];
      Ws[lq * 4 + 0][row] = w4.x; Ws[lq * 4 + 1][row] = w4.y;
      Ws[lq * 4 + 2][row] = w4.z; Ws[lq * 4 + 3][row] = w4.w;
    }
    __syncthreads();
#pragma unroll
    for (int k = 0; k < 32; ++k) {
      const float4 a = *(const float4*)&As[k][ty * 4];
      const float4 bv = *(const float4*)&Ws[k][tx * 4];
      acc[0][0] = fmaf(a.x, bv.x, acc[0][0]);
      acc[0][1] = fmaf(a.x, bv.y, acc[0][1]);
      acc[0][2] = fmaf(a.x, bv.z, acc[0][2]);
      acc[0][3] = fmaf(a.x, bv.w, acc[0][3]);
      acc[1][0] = fmaf(a.y, bv.x, acc[1][0]);
      acc[1][1] = fmaf(a.y, bv.y, acc[1][1]);
      acc[1][2] = fmaf(a.y, bv.z, acc[1][2]);
      acc[1][3] = fmaf(a.y, bv.w, acc[1][3]);
      acc[2][0] = fmaf(a.z, bv.x, acc[2][0]);
      acc[2][1] = fmaf(a.z, bv.y, acc[2][1]);
      acc[2][2] = fmaf(a.z, bv.z, acc[2][2]);
      acc[2][3] = fmaf(a.z, bv.w, acc[2][3]);
      acc[3][0] = fmaf(a.w, bv.x, acc[3][0]);
      acc[3][1] = fmaf(a.w, bv.y, acc[3][1]);
      acc[3][2] = fmaf(a.w, bv.z, acc[3][2]);
      acc[3][3] = fmaf(a.w, bv.w, acc[3][3]);
    }
    __syncthreads();
  }

  float* Pp = P + (size_t)bz * (size_t)mtiles * 64 * 512;
#pragma unroll
  for (int i = 0; i < 4; ++i) {
    float4 o;
    o.x = acc[i][0]; o.y = acc[i][1]; o.z = acc[i][2]; o.w = acc[i][3];
    *(float4*)&Pp[(size_t)(m0 + ty * 4 + i) * 512 + n0 + tx * 4] = o;
  }
}

__global__ __launch_bounds__(256) void k_fc1red(
    const float* __restrict__ P, const float* __restrict__ bias,
    float* __restrict__ O, int total) {
  const int idx = (blockIdx.x * 256 + threadIdx.x) * 4;
  const float4 p0 = *(const float4*)(P + idx);
  const float4 p1 = *(const float4*)(P + (size_t)total + idx);
  const float4 p2 = *(const float4*)(P + (size_t)2 * total + idx);
  const float4 p3 = *(const float4*)(P + (size_t)3 * total + idx);
  const float4 bv = *(const float4*)(bias + (idx & 511));
  float4 o;
  o.x = fmaxf(p0.x + p1.x + p2.x + p3.x + bv.x, 0.0f);
  o.y = fmaxf(p0.y + p1.y + p2.y + p3.y + bv.y, 0.0f);
  o.z = fmaxf(p0.z + p1.z + p2.z + p3.z + bv.z, 0.0f);
  o.w = fmaxf(p0.w + p1.w + p2.w + p3.w + bv.w, 0.0f);
  *(float4*)(O + idx) = o;
}

// ------------------------------------------------------------- FC2+softmax
__global__ __launch_bounds__(256) void k_fc2(
    const float* __restrict__ X, const float* __restrict__ W,
    const float* __restrict__ bias, float* __restrict__ out) {
  const int wv = threadIdx.x >> 6, t = threadIdx.x & 63;
  const int b = blockIdx.x * 4 + wv;
  const float* xr = X + (size_t)b * 512 + t * 8;
  const float4 x0 = *(const float4*)xr;
  const float4 x1 = *(const float4*)(xr + 4);
  float z[10];
#pragma unroll
  for (int o = 0; o < 10; ++o) {
    const float* wr = W + o * 512 + t * 8;
    const float4 w0 = *(const float4*)wr;
    const float4 w1 = *(const float4*)(wr + 4);
    float s = x0.x * w0.x;
    s = fmaf(x0.y, w0.y, s);
    s = fmaf(x0.z, w0.z, s);
    s = fmaf(x0.w, w0.w, s);
    s = fmaf(x1.x, w1.x, s);
    s = fmaf(x1.y, w1.y, s);
    s = fmaf(x1.z, w1.z, s);
    s = fmaf(x1.w, w1.w, s);
    z[o] = s;
  }
#pragma unroll
  for (int m = 1; m < 64; m <<= 1) {
#pragma unroll
    for (int o = 0; o < 10; ++o) z[o] += shx(z[o], m);
  }
#pragma unroll
  for (int o = 0; o < 10; ++o) z[o] += bias[o];
  float mx = z[0];
#pragma unroll
  for (int o = 1; o < 10; ++o) mx = fmaxf(mx, z[o]);
  float e[10];
  float ssum = 0.0f;
#pragma unroll
  for (int o = 0; o < 10; ++o) {
    e[o] = expf(z[o] - mx);
    ssum += e[o];
  }
  const float inv = 1.0f / ssum;
  if (t == 0) {
    float* dst = out + (size_t)b * 10;
#pragma unroll
    for (int o = 0; o < 10; ++o) dst[o] = e[o] * inv;
  }
}

// ------------------------------------------------------------------ launch
extern "C" void kernel_launch(void* const* d_in, const int* in_sizes, int n_in,
                              void* d_out, int out_size, void* d_ws,
                              size_t ws_size, hipStream_t stream) {
  const float* x = (const float*)d_in[0];
  const float* f1 = (const float*)d_in[1];
  const float* b1 = (const float*)d_in[2];
  const float* f2 = (const float*)d_in[3];
  const float* b2 = (const float*)d_in[4];
  const float* fc1w = (const float*)d_in[5];
  const float* fc1b = (const float*)d_in[6];
  const float* fc2w = (const float*)d_in[7];
  const float* fc2b = (const float*)d_in[8];
  float* out = (float*)d_out;
  const int B = in_sizes[0] / 3072;  // 2048

  float* kt1 = (float*)d_ws;                    // 32*1024
  float* kt2 = kt1 + 32 * 1024;                 // 64*256
  float* out2 = kt2 + 64 * 256;                 // B*4096
  float* part = out2 + (size_t)B * 4096;        // 4*B*512
  float* fc1o = part + (size_t)4 * B * 512;     // B*512

  hipLaunchKernelGGL(k_filters, dim3(96), dim3(64), 0, stream, f1, f2, kt1,
                     kt2);
  hipLaunchKernelGGL(k_conv, dim3(B), dim3(256), 0, stream, x, b1, b2, kt1,
                     kt2, out2);
  const int mtiles = B / 64;
  hipLaunchKernelGGL(k_fc1, dim3(4 * mtiles * 8), dim3(256), 0, stream, out2,
                     fc1w, part, mtiles);
  hipLaunchKernelGGL(k_fc1red, dim3((B * 512) / 1024), dim3(256), 0, stream,
                     part, fc1b, fc1o, B * 512);
  hipLaunchKernelGGL(k_fc2, dim3(B / 4), dim3(256), 0, stream, fc1o, fc2w,
                     fc2b, out);
}

// Round 2
// 256.227 us; speedup vs baseline: 1.3092x; 1.3092x over previous
//
#include <hip/hip_runtime.h>

#define DEVI __device__ __forceinline__

DEVI float shx(float v, int m) { return __shfl_xor(v, m, 64); }

// In-thread FWHT over N contiguous elements.
template <int N>
DEVI void fwht_local(float* v) {
#pragma unroll
  for (int s = 1; s < N; s <<= 1) {
#pragma unroll
    for (int k = 0; k < N; ++k) {
      if ((k & s) == 0) {
        float a = v[k], b = v[k | s];
        v[k] = a + b;
        v[k | s] = a - b;
      }
    }
  }
}

// Cross-lane xor-exchange. mask 1/2 -> DPP quad_perm (VALU pipe, no LDS);
// mask 4/8 -> ds_swizzle (no address reg needed).
template <int MASK>
DEVI float lanex(float x) {
  if constexpr (MASK == 1)
    return __int_as_float(__builtin_amdgcn_update_dpp(
        0, __float_as_int(x), 0xB1 /*quad_perm(1,0,3,2)*/, 0xF, 0xF, true));
  else if constexpr (MASK == 2)
    return __int_as_float(__builtin_amdgcn_update_dpp(
        0, __float_as_int(x), 0x4E /*quad_perm(2,3,0,1)*/, 0xF, 0xF, true));
  else
    return __int_as_float(__builtin_amdgcn_ds_swizzle(
        __float_as_int(x), (MASK << 10) | 0x1F));
}

// One cross-lane butterfly stage on N register elements.
// upper lane (bit==0) computes a+b; lower computes partner-own.
template <int N, int MASK>
DEVI void xstage(float* v, bool upper) {
  const float sgn = upper ? 1.0f : -1.0f;
#pragma unroll
  for (int k = 0; k < N; ++k) {
    float u = lanex<MASK>(v[k]);
    v[k] = fmaf(sgn, v[k], u);
  }
}

// ---- legacy shuffle-based transforms (used only in tiny k_filters) ----
template <int N>
DEVI void xbfly(float* v, int mask, int up) {
  const float sgn = up ? 1.0f : -1.0f;
#pragma unroll
  for (int k = 0; k < N; ++k) {
    float u = shx(v[k], mask);
    v[k] = fmaf(sgn, v[k], u);
  }
}

DEVI void fwht2d32(float v[16], int t) {
  fwht_local<16>(v);
  xbfly<16>(v, 1, !(t & 1));
  const int r = t >> 1;
  xbfly<16>(v, 2, !(r & 1));
  xbfly<16>(v, 4, !(r & 2));
  xbfly<16>(v, 8, !(r & 4));
  xbfly<16>(v, 16, !(r & 8));
  xbfly<16>(v, 32, !(r & 16));
}

DEVI void fwht2d16(float v[4], int l) {
  fwht_local<4>(v);
  xbfly<4>(v, 1, !(l & 1));
  xbfly<4>(v, 2, !(l & 2));
  const int r = l >> 2;
  xbfly<4>(v, 4, !(r & 1));
  xbfly<4>(v, 8, !(r & 2));
  xbfly<4>(v, 16, !(r & 4));
  xbfly<4>(v, 32, !(r & 8));
}

// ---------------------------------------------------------------- filters
// kt1 stored COL-MAJOR per filter (idx = c*32 + r) with 1/32768 folded in,
// so k_conv lanes read contiguous 16-float column slices.
// kt2 stored row-major with 1/4096 folded in.
__global__ __launch_bounds__(64) void k_filters(
    const float* __restrict__ f1, const float* __restrict__ f2,
    float* __restrict__ kt1, float* __restrict__ kt2) {
  const int blk = blockIdx.x;
  const int t = threadIdx.x;
  if (blk < 32) {
    const int f = blk;
    const int r = t >> 1, h = t & 1;
    float v[16];
#pragma unroll
    for (int k = 0; k < 16; ++k) {
      const int c = h * 16 + k;
      v[k] = (r < 3 && c < 3) ? f1[f * 9 + r * 3 + c] : 0.0f;
    }
    fwht2d32(v, t);
#pragma unroll
    for (int k = 0; k < 16; ++k)
      kt1[f * 1024 + (h * 16 + k) * 32 + r] = v[k] * (1.0f / 32768.0f);
  } else {
    const int g = blk - 32;
    const int r = t >> 2, q = t & 3;
    float v[4];
#pragma unroll
    for (int j = 0; j < 4; ++j) {
      const int c = q * 4 + j;
      v[j] = (r < 3 && c < 3) ? f2[g * 9 + r * 3 + c] : 0.0f;
    }
    fwht2d16(v, t);
#pragma unroll
    for (int j = 0; j < 4; ++j)
      kt2[g * 256 + r * 16 + q * 4 + j] = v[j] * (1.0f / 4096.0f);
  }
}

// ---------------------------------------------------------- fused conv1+conv2
// Layout L1 (32x32 tile): lane t = (row r=t>>1, col-half c4=t&1), 16 col-
//   contiguous elems intra. Column-dim FWHT = 4 intra stages + 1 DPP stage.
// Layout L2: lane t = (col c=t>>1, row-half r4=t&1), 16 row-contiguous intra.
// Row-dim FWHT likewise. L1<->L2 via per-wave private LDS transpose
// (stride 34 floats: scalar writes conflict-free, b64 reads 4-way max).
__global__ __launch_bounds__(256) void k_conv(
    const float* __restrict__ x, const float* __restrict__ bias1,
    const float* __restrict__ bias2, const float* __restrict__ kt1,
    const float* __restrict__ kt2, float* __restrict__ out2) {
  __shared__ float tb[4 * 1160];
  const int b = blockIdx.x;
  const int tid = threadIdx.x;
  const int wv = tid >> 6, t = tid & 63;
  float* buf = tb + wv * 1160;
  // transpose write: elem (r,c) -> buf[34*c + r]; both transposes reduce to
  // the same per-lane bases by symmetry.
  const int wbase = 544 * (t & 1) + (t >> 1);
  const int rbase = 34 * (t >> 1) + 16 * (t & 1);

  // ---- load S = sum_c x[b,c] directly in L1 layout (L1/L2-cached re-reads)
  float Ts[16];
  {
    const float* xb = x + (size_t)b * 3072 + (t >> 1) * 32 + (t & 1) * 16;
#pragma unroll
    for (int q = 0; q < 4; ++q) {
      float4 a0 = *(const float4*)(xb + 4 * q);
      float4 a1 = *(const float4*)(xb + 1024 + 4 * q);
      float4 a2 = *(const float4*)(xb + 2048 + 4 * q);
      Ts[4 * q + 0] = a0.x + a1.x + a2.x;
      Ts[4 * q + 1] = a0.y + a1.y + a2.y;
      Ts[4 * q + 2] = a0.z + a1.z + a2.z;
      Ts[4 * q + 3] = a0.w + a1.w + a2.w;
    }
  }
  // forward: col-dim in L1
  fwht_local<16>(Ts);
  xstage<16, 1>(Ts, !(t & 1));
  // transpose L1 -> L2
#pragma unroll
  for (int k = 0; k < 16; ++k) buf[wbase + 34 * k] = Ts[k];
  asm volatile("" ::: "memory");
#pragma unroll
  for (int j = 0; j < 8; ++j) {
    float2 v2 = *(const float2*)&buf[rbase + 2 * j];
    Ts[2 * j] = v2.x;
    Ts[2 * j + 1] = v2.y;
  }
  asm volatile("" ::: "memory");
  // forward: row-dim in L2  -> Ts = FWHT2D(S) in L2 layout
  fwht_local<16>(Ts);
  xstage<16, 1>(Ts, !(t & 1));

  float acc[8];
#pragma unroll
  for (int j = 0; j < 8; ++j) acc[j] = 0.0f;

  // ---- 8 conv1 filters per wave
  for (int i = 0; i < 8; ++i) {
    const int f = wv * 8 + i;
    const float* kp = kt1 + f * 1024 + t * 16;
    float u[16];
#pragma unroll
    for (int q = 0; q < 4; ++q) {
      float4 kv = *(const float4*)(kp + 4 * q);
      u[4 * q + 0] = Ts[4 * q + 0] * kv.x;
      u[4 * q + 1] = Ts[4 * q + 1] * kv.y;
      u[4 * q + 2] = Ts[4 * q + 2] * kv.z;
      u[4 * q + 3] = Ts[4 * q + 3] * kv.w;
    }
    // inverse row-dim (L2)
    fwht_local<16>(u);
    xstage<16, 1>(u, !(t & 1));
    // transpose L2 -> L1
#pragma unroll
    for (int k = 0; k < 16; ++k) buf[wbase + 34 * k] = u[k];
    asm volatile("" ::: "memory");
#pragma unroll
    for (int j = 0; j < 8; ++j) {
      float2 v2 = *(const float2*)&buf[rbase + 2 * j];
      u[2 * j] = v2.x;
      u[2 * j + 1] = v2.y;
    }
    asm volatile("" ::: "memory");
    // inverse col-dim (L1)
    fwht_local<16>(u);
    xstage<16, 1>(u, !(t & 1));
    // bias + relu (scale already folded into kt1)
    const float bb = bias1[f];
#pragma unroll
    for (int k = 0; k < 16; ++k) u[k] = fmaxf(u[k] + bb, 0.0f);
    // pool rows: r0 is lane bit1 -> DPP mask 2
#pragma unroll
    for (int k = 0; k < 16; ++k) u[k] = fmaxf(u[k], lanex<2>(u[k]));
    // pool cols + accumulate channel-sum S2
#pragma unroll
    for (int j = 0; j < 8; ++j) acc[j] += fmaxf(u[2 * j], u[2 * j + 1]);
  }

  // ---- per-wave partial S2 (16x16) -> LDS (stride 20, b128-aligned)
  if (!(t & 2)) {
    const int pb = (t >> 2) * 20 + (t & 1) * 8;
    *(float4*)&buf[pb] = make_float4(acc[0], acc[1], acc[2], acc[3]);
    *(float4*)&buf[pb + 4] = make_float4(acc[4], acc[5], acc[6], acc[7]);
  }
  __syncthreads();

  // ---- conv2: lane = (filter-slot f2=t>>4, row rr=t&15), full 16-col row
  const int f2 = t >> 4, rr = t & 15;
  float T2[16];
#pragma unroll
  for (int q = 0; q < 4; ++q) {
    float4 s = make_float4(0.f, 0.f, 0.f, 0.f);
#pragma unroll
    for (int w2 = 0; w2 < 4; ++w2) {
      const float4 v = *(const float4*)&tb[w2 * 1160 + rr * 20 + 4 * q];
      s.x += v.x; s.y += v.y; s.z += v.z; s.w += v.w;
    }
    T2[4 * q + 0] = s.x;
    T2[4 * q + 1] = s.y;
    T2[4 * q + 2] = s.z;
    T2[4 * q + 3] = s.w;
  }
  // forward FWHT2D_16: cols intra, rows via lane bits 0..3
  fwht_local<16>(T2);
  xstage<16, 1>(T2, !(t & 1));
  xstage<16, 2>(T2, !(t & 2));
  xstage<16, 4>(T2, !(t & 4));
  xstage<16, 8>(T2, !(t & 8));

#pragma unroll
  for (int it = 0; it < 4; ++it) {
    const int g = wv * 16 + it * 4 + f2;
    const float* kp2 = kt2 + g * 256 + rr * 16;
    float u[16];
#pragma unroll
    for (int q = 0; q < 4; ++q) {
      float4 kv = *(const float4*)(kp2 + 4 * q);
      u[4 * q + 0] = T2[4 * q + 0] * kv.x;
      u[4 * q + 1] = T2[4 * q + 1] * kv.y;
      u[4 * q + 2] = T2[4 * q + 2] * kv.z;
      u[4 * q + 3] = T2[4 * q + 3] * kv.w;
    }
    fwht_local<16>(u);
    xstage<16, 1>(u, !(t & 1));
    xstage<16, 2>(u, !(t & 2));
    xstage<16, 4>(u, !(t & 4));
    xstage<16, 8>(u, !(t & 8));
    const float bb = bias2[g];
#pragma unroll
    for (int k = 0; k < 16; ++k) u[k] = fmaxf(u[k] + bb, 0.0f);
    // pool rows: r0 = lane bit0 -> DPP mask 1
#pragma unroll
    for (int k = 0; k < 16; ++k) u[k] = fmaxf(u[k], lanex<1>(u[k]));
    float p0 = fmaxf(u[0], u[1]), p1 = fmaxf(u[2], u[3]);
    float p2 = fmaxf(u[4], u[5]), p3 = fmaxf(u[6], u[7]);
    float p4 = fmaxf(u[8], u[9]), p5 = fmaxf(u[10], u[11]);
    float p6 = fmaxf(u[12], u[13]), p7 = fmaxf(u[14], u[15]);
    if (!(t & 1)) {
      float* dst = out2 + (size_t)b * 4096 + g * 64 + (rr >> 1) * 8;
      *(float4*)dst = make_float4(p0, p1, p2, p3);
      *(float4*)(dst + 4) = make_float4(p4, p5, p6, p7);
    }
  }
}

// ------------------------------------------------------------------- FC1
__global__ __launch_bounds__(256) void k_fc1(
    const float* __restrict__ A, const float* __restrict__ W,
    float* __restrict__ P, int mtiles) {
  __shared__ float As[32][68];
  __shared__ float Ws[32][68];
  const int tiles = mtiles * 8;
  const int bz = blockIdx.x / tiles;
  const int rem = blockIdx.x % tiles;
  const int m0 = (rem >> 3) * 64;
  const int n0 = (rem & 7) * 64;
  const int k0 = bz * 1024;
  const int tid = threadIdx.x;
  const int tx = tid & 15, ty = tid >> 4;
  const int lrow = tid >> 3, lq = tid & 7;

  float acc[4][4];
#pragma unroll
  for (int i = 0; i < 4; ++i)
#pragma unroll
    for (int j = 0; j < 4; ++j) acc[i][j] = 0.0f;

  for (int kk = 0; kk < 1024; kk += 32) {
#pragma unroll
    for (int half = 0; half < 2; ++half) {
      const int row = lrow + half * 32;
      const float4 a4 =
          *(const float4*)&A[(size_t)(m0 + row) * 4096 + k0 + kk + lq * 4];
      As[lq * 4 + 0][row] = a4.x; As[lq * 4 + 1][row] = a4.y;
      As[lq * 4 + 2][row] = a4.z; As[lq * 4 + 3][row] = a4.w;
      const float4 w4 =
          *(const float4*)&W[(size_t)(n0 + row) * 4096 + k0 + kk + lq * 4];
      Ws[lq * 4 + 0][row] = w4.x; Ws[lq * 4 + 1][row] = w4.y;
      Ws[lq * 4 + 2][row] = w4.z; Ws[lq * 4 + 3][row] = w4.w;
    }
    __syncthreads();
#pragma unroll
    for (int k = 0; k < 32; ++k) {
      const float4 a = *(const float4*)&As[k][ty * 4];
      const float4 bv = *(const float4*)&Ws[k][tx * 4];
      acc[0][0] = fmaf(a.x, bv.x, acc[0][0]);
      acc[0][1] = fmaf(a.x, bv.y, acc[0][1]);
      acc[0][2] = fmaf(a.x, bv.z, acc[0][2]);
      acc[0][3] = fmaf(a.x, bv.w, acc[0][3]);
      acc[1][0] = fmaf(a.y, bv.x, acc[1][0]);
      acc[1][1] = fmaf(a.y, bv.y, acc[1][1]);
      acc[1][2] = fmaf(a.y, bv.z, acc[1][2]);
      acc[1][3] = fmaf(a.y, bv.w, acc[1][3]);
      acc[2][0] = fmaf(a.z, bv.x, acc[2][0]);
      acc[2][1] = fmaf(a.z, bv.y, acc[2][1]);
      acc[2][2] = fmaf(a.z, bv.z, acc[2][2]);
      acc[2][3] = fmaf(a.z, bv.w, acc[2][3]);
      acc[3][0] = fmaf(a.w, bv.x, acc[3][0]);
      acc[3][1] = fmaf(a.w, bv.y, acc[3][1]);
      acc[3][2] = fmaf(a.w, bv.z, acc[3][2]);
      acc[3][3] = fmaf(a.w, bv.w, acc[3][3]);
    }
    __syncthreads();
  }

  float* Pp = P + (size_t)bz * (size_t)mtiles * 64 * 512;
#pragma unroll
  for (int i = 0; i < 4; ++i) {
    float4 o;
    o.x = acc[i][0]; o.y = acc[i][1]; o.z = acc[i][2]; o.w = acc[i][3];
    *(float4*)&Pp[(size_t)(m0 + ty * 4 + i) * 512 + n0 + tx * 4] = o;
  }
}

__global__ __launch_bounds__(256) void k_fc1red(
    const float* __restrict__ P, const float* __restrict__ bias,
    float* __restrict__ O, int total) {
  const int idx = (blockIdx.x * 256 + threadIdx.x) * 4;
  const float4 p0 = *(const float4*)(P + idx);
  const float4 p1 = *(const float4*)(P + (size_t)total + idx);
  const float4 p2 = *(const float4*)(P + (size_t)2 * total + idx);
  const float4 p3 = *(const float4*)(P + (size_t)3 * total + idx);
  const float4 bv = *(const float4*)(bias + (idx & 511));
  float4 o;
  o.x = fmaxf(p0.x + p1.x + p2.x + p3.x + bv.x, 0.0f);
  o.y = fmaxf(p0.y + p1.y + p2.y + p3.y + bv.y, 0.0f);
  o.z = fmaxf(p0.z + p1.z + p2.z + p3.z + bv.z, 0.0f);
  o.w = fmaxf(p0.w + p1.w + p2.w + p3.w + bv.w, 0.0f);
  *(float4*)(O + idx) = o;
}

// ------------------------------------------------------------- FC2+softmax
__global__ __launch_bounds__(256) void k_fc2(
    const float* __restrict__ X, const float* __restrict__ W,
    const float* __restrict__ bias, float* __restrict__ out) {
  const int wv = threadIdx.x >> 6, t = threadIdx.x & 63;
  const int b = blockIdx.x * 4 + wv;
  const float* xr = X + (size_t)b * 512 + t * 8;
  const float4 x0 = *(const float4*)xr;
  const float4 x1 = *(const float4*)(xr + 4);
  float z[10];
#pragma unroll
  for (int o = 0; o < 10; ++o) {
    const float* wr = W + o * 512 + t * 8;
    const float4 w0 = *(const float4*)wr;
    const float4 w1 = *(const float4*)(wr + 4);
    float s = x0.x * w0.x;
    s = fmaf(x0.y, w0.y, s);
    s = fmaf(x0.z, w0.z, s);
    s = fmaf(x0.w, w0.w, s);
    s = fmaf(x1.x, w1.x, s);
    s = fmaf(x1.y, w1.y, s);
    s = fmaf(x1.z, w1.z, s);
    s = fmaf(x1.w, w1.w, s);
    z[o] = s;
  }
#pragma unroll
  for (int m = 1; m < 64; m <<= 1) {
#pragma unroll
    for (int o = 0; o < 10; ++o) z[o] += shx(z[o], m);
  }
#pragma unroll
  for (int o = 0; o < 10; ++o) z[o] += bias[o];
  float mx = z[0];
#pragma unroll
  for (int o = 1; o < 10; ++o) mx = fmaxf(mx, z[o]);
  float e[10];
  float ssum = 0.0f;
#pragma unroll
  for (int o = 0; o < 10; ++o) {
    e[o] = expf(z[o] - mx);
    ssum += e[o];
  }
  const float inv = 1.0f / ssum;
  if (t == 0) {
    float* dst = out + (size_t)b * 10;
#pragma unroll
    for (int o = 0; o < 10; ++o) dst[o] = e[o] * inv;
  }
}

// ------------------------------------------------------------------ launch
extern "C" void kernel_launch(void* const* d_in, const int* in_sizes, int n_in,
                              void* d_out, int out_size, void* d_ws,
                              size_t ws_size, hipStream_t stream) {
  const float* x = (const float*)d_in[0];
  const float* f1 = (const float*)d_in[1];
  const float* b1 = (const float*)d_in[2];
  const float* f2 = (const float*)d_in[3];
  const float* b2 = (const float*)d_in[4];
  const float* fc1w = (const float*)d_in[5];
  const float* fc1b = (const float*)d_in[6];
  const float* fc2w = (const float*)d_in[7];
  const float* fc2b = (const float*)d_in[8];
  float* out = (float*)d_out;
  const int B = in_sizes[0] / 3072;  // 2048

  float* kt1 = (float*)d_ws;                    // 32*1024
  float* kt2 = kt1 + 32 * 1024;                 // 64*256
  float* out2 = kt2 + 64 * 256;                 // B*4096
  float* part = out2 + (size_t)B * 4096;        // 4*B*512
  float* fc1o = part + (size_t)4 * B * 512;     // B*512

  hipLaunchKernelGGL(k_filters, dim3(96), dim3(64), 0, stream, f1, f2, kt1,
                     kt2);
  hipLaunchKernelGGL(k_conv, dim3(B), dim3(256), 0, stream, x, b1, b2, kt1,
                     kt2, out2);
  const int mtiles = B / 64;
  hipLaunchKernelGGL(k_fc1, dim3(4 * mtiles * 8), dim3(256), 0, stream, out2,
                     fc1w, part, mtiles);
  hipLaunchKernelGGL(k_fc1red, dim3((B * 512) / 1024), dim3(256), 0, stream,
                     part, fc1b, fc1o, B * 512);
  hipLaunchKernelGGL(k_fc2, dim3(B / 4), dim3(256), 0, stream, fc1o, fc2w,
                     fc2b, out);
}